// Round 1
// baseline (666.101 us; speedup 1.0000x reference)
//
#include <hip/hip_runtime.h>
#include <hip/hip_bf16.h>
#include <cstdint>

#define T_TOK 4096
#define DMODEL 1024
#define HDIM 2048
#define NEXP 8

typedef short bf16x8 __attribute__((ext_vector_type(8)));
typedef float f32x4 __attribute__((ext_vector_type(4)));
typedef uint32_t u32x4 __attribute__((ext_vector_type(4)));

__device__ __forceinline__ uint32_t cvt_pk_bf16(float lo, float hi) {
  uint32_t d;
  asm("v_cvt_pk_bf16_f32 %0, %1, %2" : "=v"(d) : "v"(lo), "v"(hi));
  return d;
}
__device__ __forceinline__ unsigned short f2bf(float f) {
  uint32_t d;
  asm("v_cvt_pk_bf16_f32 %0, %1, %1" : "=v"(d) : "v"(f));
  return (unsigned short)d;
}
__device__ __forceinline__ float gelu_erf(float v) {
  return 0.5f * v * (1.0f + erff(v * 0.70710678118654752f));
}

// ---------------- router: one wave per token ----------------
__global__ __launch_bounds__(256) void router_kernel(
    const float* __restrict__ x, const float* __restrict__ Wr,
    int* __restrict__ cursor, int* __restrict__ cnt1,
    float* __restrict__ psum, int* __restrict__ perm, float* __restrict__ pw) {
  __shared__ float4 sW[8 * 256];
  __shared__ float sP[8];
  int tid = threadIdx.x;
  const float4* W4 = (const float4*)Wr;
  for (int i = tid; i < 2048; i += 256) sW[i] = W4[i];
  if (tid < 8) sP[tid] = 0.f;
  __syncthreads();

  int lane = tid & 63, wid = tid >> 6;
  int t = blockIdx.x * 4 + wid;
  float acc[8] = {0.f, 0.f, 0.f, 0.f, 0.f, 0.f, 0.f, 0.f};
  const float4* x4 = (const float4*)(x + (size_t)t * DMODEL);
#pragma unroll
  for (int it = 0; it < 4; ++it) {
    float4 xv = x4[it * 64 + lane];
#pragma unroll
    for (int e = 0; e < 8; ++e) {
      float4 wv = sW[e * 256 + it * 64 + lane];
      acc[e] += xv.x * wv.x + xv.y * wv.y + xv.z * wv.z + xv.w * wv.w;
    }
  }
#pragma unroll
  for (int e = 0; e < 8; ++e)
    for (int off = 32; off; off >>= 1) acc[e] += __shfl_xor(acc[e], off);

  // softmax (all lanes redundantly)
  float mx = acc[0];
#pragma unroll
  for (int e = 1; e < 8; ++e) mx = fmaxf(mx, acc[e]);
  float ex[8], s = 0.f;
#pragma unroll
  for (int e = 0; e < 8; ++e) { ex[e] = expf(acc[e] - mx); s += ex[e]; }
  float inv = 1.f / s;
  int e0 = 0;
#pragma unroll
  for (int e = 1; e < 8; ++e) if (acc[e] > acc[e0]) e0 = e;
  int e1 = (e0 == 0) ? 1 : 0;
#pragma unroll
  for (int e = 0; e < 8; ++e) if (e != e0 && acc[e] > acc[e1]) e1 = e;

  if (lane == 0) {
#pragma unroll
    for (int e = 0; e < 8; ++e) atomicAdd(&sP[e], ex[e] * inv);
    atomicAdd(&cnt1[e0], 1);
    int s0 = atomicAdd(&cursor[e0], 1);
    perm[e0 * 4096 + s0] = t; pw[e0 * 4096 + s0] = ex[e0] * inv;
    int s1 = atomicAdd(&cursor[e1], 1);
    perm[e1 * 4096 + s1] = t; pw[e1 * 4096 + s1] = ex[e1] * inv;
  }
  __syncthreads();
  if (tid < 8) atomicAdd(&psum[tid], sP[tid]);
}

// ---------------- finalize: bases + aux loss ----------------
__global__ void finalize_kernel(const int* __restrict__ cursor,
                                const int* __restrict__ cnt1,
                                const float* __restrict__ psum,
                                int* __restrict__ base, float* __restrict__ aux_out) {
  if (threadIdx.x == 0) {
    int b = 0;
    for (int e = 0; e < 8; ++e) { base[e] = b; b += cursor[e]; }
    base[8] = b;  // == 8192; shared expert rows start here
    float aux = 0.f;
    for (int e = 0; e < 8; ++e)
      aux += ((float)cnt1[e] * (1.f / T_TOK)) * (psum[e] * (1.f / T_TOK));
    aux_out[0] = 0.01f * 8.f * aux;
  }
}

// ---------------- fused up+gate GEMM: h = gelu(x@w1^T) * (x@w3^T) ----------------
__global__ __launch_bounds__(256, 2) void gemm_upgate(
    const float* __restrict__ x,
    const float* __restrict__ w1, const float* __restrict__ w3,
    const float* __restrict__ w1s, const float* __restrict__ w3s,
    const int* __restrict__ cursor, const int* __restrict__ base,
    const int* __restrict__ perm, unsigned short* __restrict__ hbuf) {
  int e = blockIdx.z, mt = blockIdx.y, nt = blockIdx.x;
  int cnt = (e < 8) ? cursor[e] : 4096;
  if (mt * 128 >= cnt) return;
  int hb = base[e];
  const float* B1 = (e < 8) ? w1 + (size_t)e * HDIM * DMODEL : w1s;
  const float* B3 = (e < 8) ? w3 + (size_t)e * HDIM * DMODEL : w3s;

  __shared__ unsigned short As[128 * 32];
  __shared__ unsigned short Bs1[128 * 32];
  __shared__ unsigned short Bs3[128 * 32];

  int tid = threadIdx.x;
  int r = tid >> 1, cg = (tid & 1) * 16;
  int slot = mt * 128 + r;
  int tok = (e == 8) ? slot : ((slot < cnt) ? perm[e * 4096 + slot] : 0);
  const float* aSrc = x + (size_t)tok * DMODEL + cg;
  const float* b1Src = B1 + (size_t)(nt * 128 + r) * DMODEL + cg;
  const float* b3Src = B3 + (size_t)(nt * 128 + r) * DMODEL + cg;

  int lane = tid & 63;
  int wr = tid >> 7, wc = (tid >> 6) & 1;
  int fr = lane & 15, ko = (lane >> 4) * 8;

  f32x4 acc1[4][4] = {}; f32x4 acc3[4][4] = {};

  for (int k0 = 0; k0 < DMODEL; k0 += 32) {
    {
      const float4* s = (const float4*)(aSrc + k0);
      float4 v0 = s[0], v1 = s[1], v2 = s[2], v3 = s[3];
      u32x4 p0 = {cvt_pk_bf16(v0.x, v0.y), cvt_pk_bf16(v0.z, v0.w),
                  cvt_pk_bf16(v1.x, v1.y), cvt_pk_bf16(v1.z, v1.w)};
      u32x4 p1 = {cvt_pk_bf16(v2.x, v2.y), cvt_pk_bf16(v2.z, v2.w),
                  cvt_pk_bf16(v3.x, v3.y), cvt_pk_bf16(v3.z, v3.w)};
      *(u32x4*)&As[r * 32 + cg] = p0;
      *(u32x4*)&As[r * 32 + cg + 8] = p1;
    }
    {
      const float4* s = (const float4*)(b1Src + k0);
      float4 v0 = s[0], v1 = s[1], v2 = s[2], v3 = s[3];
      u32x4 p0 = {cvt_pk_bf16(v0.x, v0.y), cvt_pk_bf16(v0.z, v0.w),
                  cvt_pk_bf16(v1.x, v1.y), cvt_pk_bf16(v1.z, v1.w)};
      u32x4 p1 = {cvt_pk_bf16(v2.x, v2.y), cvt_pk_bf16(v2.z, v2.w),
                  cvt_pk_bf16(v3.x, v3.y), cvt_pk_bf16(v3.z, v3.w)};
      *(u32x4*)&Bs1[r * 32 + cg] = p0;
      *(u32x4*)&Bs1[r * 32 + cg + 8] = p1;
    }
    {
      const float4* s = (const float4*)(b3Src + k0);
      float4 v0 = s[0], v1 = s[1], v2 = s[2], v3 = s[3];
      u32x4 p0 = {cvt_pk_bf16(v0.x, v0.y), cvt_pk_bf16(v0.z, v0.w),
                  cvt_pk_bf16(v1.x, v1.y), cvt_pk_bf16(v1.z, v1.w)};
      u32x4 p1 = {cvt_pk_bf16(v2.x, v2.y), cvt_pk_bf16(v2.z, v2.w),
                  cvt_pk_bf16(v3.x, v3.y), cvt_pk_bf16(v3.z, v3.w)};
      *(u32x4*)&Bs3[r * 32 + cg] = p0;
      *(u32x4*)&Bs3[r * 32 + cg + 8] = p1;
    }
    __syncthreads();
    bf16x8 af[4], b1f[4], b3f[4];
#pragma unroll
    for (int m = 0; m < 4; ++m)
      af[m] = *(const bf16x8*)&As[(wr * 64 + m * 16 + fr) * 32 + ko];
#pragma unroll
    for (int n = 0; n < 4; ++n) {
      b1f[n] = *(const bf16x8*)&Bs1[(wc * 64 + n * 16 + fr) * 32 + ko];
      b3f[n] = *(const bf16x8*)&Bs3[(wc * 64 + n * 16 + fr) * 32 + ko];
    }
#pragma unroll
    for (int m = 0; m < 4; ++m)
#pragma unroll
      for (int n = 0; n < 4; ++n) {
        acc1[m][n] = __builtin_amdgcn_mfma_f32_16x16x32_bf16(af[m], b1f[n], acc1[m][n], 0, 0, 0);
        acc3[m][n] = __builtin_amdgcn_mfma_f32_16x16x32_bf16(af[m], b3f[n], acc3[m][n], 0, 0, 0);
      }
    __syncthreads();
  }

#pragma unroll
  for (int m = 0; m < 4; ++m) {
#pragma unroll
    for (int n = 0; n < 4; ++n) {
      int col = nt * 128 + wc * 64 + n * 16 + fr;
      f32x4 u = acc1[m][n], g = acc3[m][n];
#pragma unroll
      for (int j = 0; j < 4; ++j) {
        int rl = wr * 64 + m * 16 + (lane >> 4) * 4 + j;
        int sl = mt * 128 + rl;
        if (sl < cnt) {
          float hv = gelu_erf(u[j]) * g[j];
          hbuf[(size_t)(hb + sl) * HDIM + col] = f2bf(hv);
        }
      }
    }
  }
}

// ---------------- down GEMM + weighted scatter ----------------
__global__ __launch_bounds__(256, 2) void gemm_down(
    const unsigned short* __restrict__ hbuf,
    const float* __restrict__ w2, const float* __restrict__ w2s,
    const int* __restrict__ cursor, const int* __restrict__ base,
    const int* __restrict__ perm, const float* __restrict__ pw,
    float* __restrict__ out) {
  int e = blockIdx.z, mt = blockIdx.y, nt = blockIdx.x;
  int cnt = (e < 8) ? cursor[e] : 4096;
  if (mt * 128 >= cnt) return;
  int hb = base[e];
  const float* B = (e < 8) ? w2 + (size_t)e * DMODEL * HDIM : w2s;

  __shared__ unsigned short As[128 * 32];
  __shared__ unsigned short Bs[128 * 32];

  int tid = threadIdx.x;
  int r = tid >> 1, cg = (tid & 1) * 16;
  const unsigned short* aSrc = hbuf + (size_t)(hb + mt * 128 + r) * HDIM + cg;
  const float* bSrc = B + (size_t)(nt * 128 + r) * HDIM + cg;

  int lane = tid & 63;
  int wr = tid >> 7, wc = (tid >> 6) & 1;
  int fr = lane & 15, ko = (lane >> 4) * 8;

  f32x4 acc[4][4] = {};

  for (int k0 = 0; k0 < HDIM; k0 += 32) {
    {
      const u32x4* s = (const u32x4*)(aSrc + k0);
      u32x4 a0 = s[0], a1 = s[1];
      *(u32x4*)&As[r * 32 + cg] = a0;
      *(u32x4*)&As[r * 32 + cg + 8] = a1;
    }
    {
      const float4* s = (const float4*)(bSrc + k0);
      float4 v0 = s[0], v1 = s[1], v2 = s[2], v3 = s[3];
      u32x4 p0 = {cvt_pk_bf16(v0.x, v0.y), cvt_pk_bf16(v0.z, v0.w),
                  cvt_pk_bf16(v1.x, v1.y), cvt_pk_bf16(v1.z, v1.w)};
      u32x4 p1 = {cvt_pk_bf16(v2.x, v2.y), cvt_pk_bf16(v2.z, v2.w),
                  cvt_pk_bf16(v3.x, v3.y), cvt_pk_bf16(v3.z, v3.w)};
      *(u32x4*)&Bs[r * 32 + cg] = p0;
      *(u32x4*)&Bs[r * 32 + cg + 8] = p1;
    }
    __syncthreads();
    bf16x8 af[4], bf[4];
#pragma unroll
    for (int m = 0; m < 4; ++m)
      af[m] = *(const bf16x8*)&As[(wr * 64 + m * 16 + fr) * 32 + ko];
#pragma unroll
    for (int n = 0; n < 4; ++n)
      bf[n] = *(const bf16x8*)&Bs[(wc * 64 + n * 16 + fr) * 32 + ko];
#pragma unroll
    for (int m = 0; m < 4; ++m)
#pragma unroll
      for (int n = 0; n < 4; ++n)
        acc[m][n] = __builtin_amdgcn_mfma_f32_16x16x32_bf16(af[m], bf[n], acc[m][n], 0, 0, 0);
    __syncthreads();
  }

#pragma unroll
  for (int m = 0; m < 4; ++m) {
#pragma unroll
    for (int n = 0; n < 4; ++n) {
      int col = nt * 128 + wc * 64 + n * 16 + fr;
      f32x4 a = acc[m][n];
#pragma unroll
      for (int j = 0; j < 4; ++j) {
        int rl = wr * 64 + m * 16 + (lane >> 4) * 4 + j;
        int sl = mt * 128 + rl;
        if (sl < cnt) {
          int tok; float p;
          if (e == 8) { tok = sl; p = 1.f; }
          else { tok = perm[e * 4096 + sl]; p = pw[e * 4096 + sl]; }
          atomicAdd(&out[(size_t)tok * DMODEL + col], p * a[j]);
        }
      }
    }
  }
}

extern "C" void kernel_launch(void* const* d_in, const int* in_sizes, int n_in,
                              void* d_out, int out_size, void* d_ws, size_t ws_size,
                              hipStream_t stream) {
  const float* x   = (const float*)d_in[0];
  const float* Wr  = (const float*)d_in[1];
  const float* w1  = (const float*)d_in[2];
  const float* w2  = (const float*)d_in[3];
  const float* w3  = (const float*)d_in[4];
  const float* w1s = (const float*)d_in[5];
  const float* w2s = (const float*)d_in[6];
  const float* w3s = (const float*)d_in[7];
  float* out = (float*)d_out;

  char* ws = (char*)d_ws;
  const size_t H_OFF = 0;                               // 12288*2048 bf16 = 50331648 B
  const size_t PERM_OFF = 50331648;                     // 8*4096 int
  const size_t PW_OFF   = PERM_OFF + 131072;            // 8*4096 float
  const size_t CTRL_OFF = PW_OFF + 131072;
  unsigned short* hbuf = (unsigned short*)(ws + H_OFF);
  int*   perm   = (int*)(ws + PERM_OFF);
  float* pw     = (float*)(ws + PW_OFF);
  int*   cursor = (int*)(ws + CTRL_OFF);                // 8 ints
  int*   cnt1   = (int*)(ws + CTRL_OFF + 32);           // 8 ints
  float* psum   = (float*)(ws + CTRL_OFF + 64);         // 8 floats
  int*   base   = (int*)(ws + CTRL_OFF + 96);           // 9 ints

  hipMemsetAsync(d_out, 0, (size_t)out_size * sizeof(float), stream);
  hipMemsetAsync(ws + CTRL_OFF, 0, 96, stream);

  router_kernel<<<1024, 256, 0, stream>>>(x, Wr, cursor, cnt1, psum, perm, pw);
  finalize_kernel<<<1, 64, 0, stream>>>(cursor, cnt1, psum, base,
                                        out + (size_t)T_TOK * DMODEL);
  gemm_upgate<<<dim3(16, 32, 9), 256, 0, stream>>>(x, w1, w3, w1s, w3s,
                                                   cursor, base, perm, hbuf);
  gemm_down<<<dim3(8, 32, 9), 256, 0, stream>>>(hbuf, w2, w2s,
                                                cursor, base, perm, pw, out);
}

// Round 2
// 488.654 us; speedup vs baseline: 1.3631x; 1.3631x over previous
//
#include <hip/hip_runtime.h>
#include <hip/hip_bf16.h>
#include <cstdint>

#define T_TOK 4096
#define DMODEL 1024
#define HDIM 2048

typedef short bf16x8 __attribute__((ext_vector_type(8)));
typedef float f32x4 __attribute__((ext_vector_type(4)));
typedef uint32_t u32x4 __attribute__((ext_vector_type(4)));

__device__ __forceinline__ uint32_t cvt_pk_bf16(float lo, float hi) {
  uint32_t d;
  asm("v_cvt_pk_bf16_f32 %0, %1, %2" : "=v"(d) : "v"(lo), "v"(hi));
  return d;
}
__device__ __forceinline__ unsigned short f2bf(float f) {
  uint32_t d;
  asm("v_cvt_pk_bf16_f32 %0, %1, %1" : "=v"(d) : "v"(f));
  return (unsigned short)d;
}
__device__ __forceinline__ float gelu_erf(float v) {
  return 0.5f * v * (1.0f + erff(v * 0.70710678118654752f));
}
__device__ __forceinline__ void gload16(const void* g, void* lds) {
  __builtin_amdgcn_global_load_lds((const __attribute__((address_space(1))) void*)g,
                                   (__attribute__((address_space(3))) void*)lds, 16, 0, 0);
}
__device__ __forceinline__ u32x4 pk8(const float* s) {
  float4 v0 = ((const float4*)s)[0], v1 = ((const float4*)s)[1];
  u32x4 p = {cvt_pk_bf16(v0.x, v0.y), cvt_pk_bf16(v0.z, v0.w),
             cvt_pk_bf16(v1.x, v1.y), cvt_pk_bf16(v1.z, v1.w)};
  return p;
}

// ---------------- conversions ----------------
__global__ __launch_bounds__(256) void convert_x(const float* __restrict__ x,
                                                 short* __restrict__ xb) {
  size_t i = (size_t)blockIdx.x * 256 + threadIdx.x;  // one 8-elem chunk
  *(u32x4*)(xb + i * 8) = pk8(x + i * 8);
}

// wu/wg fragment layout per expert: [h16:128][d32:32][lane:64][8 bf16]
__global__ __launch_bounds__(256) void convert_w13(
    const float* __restrict__ w1, const float* __restrict__ w3,
    const float* __restrict__ w1s, const float* __restrict__ w3s,
    short* __restrict__ wu, short* __restrict__ wg) {
  int id = blockIdx.x * 256 + threadIdx.x;
  int e = id >> 18, rem = id & 262143;
  int h16 = rem >> 11, d32 = (rem >> 6) & 31, ln = rem & 63;
  size_t so = (size_t)(h16 * 16 + (ln & 15)) * DMODEL + d32 * 32 + (ln >> 4) * 8;
  const float* s1 = (e < 8) ? w1 + (size_t)e * 2097152 + so : w1s + so;
  const float* s3 = (e < 8) ? w3 + (size_t)e * 2097152 + so : w3s + so;
  *(u32x4*)(wu + (size_t)id * 8) = pk8(s1);
  *(u32x4*)(wg + (size_t)id * 8) = pk8(s3);
}

// wd fragment layout per expert: [d16:64][h32:64][lane:64][8 bf16]
__global__ __launch_bounds__(256) void convert_w2(
    const float* __restrict__ w2, const float* __restrict__ w2s,
    short* __restrict__ wd) {
  int id = blockIdx.x * 256 + threadIdx.x;
  int e = id >> 18, rem = id & 262143;
  int d16 = rem >> 12, h32 = (rem >> 6) & 63, ln = rem & 63;
  size_t so = (size_t)(d16 * 16 + (ln & 15)) * HDIM + h32 * 32 + (ln >> 4) * 8;
  const float* s2 = (e < 8) ? w2 + (size_t)e * 2097152 + so : w2s + so;
  *(u32x4*)(wd + (size_t)id * 8) = pk8(s2);
}

// ---------------- router: one wave per token ----------------
__global__ __launch_bounds__(256) void router_kernel(
    const float* __restrict__ x, const float* __restrict__ Wr,
    int* __restrict__ cursor, int* __restrict__ cnt1,
    float* __restrict__ psum, int* __restrict__ perm, float* __restrict__ pw) {
  __shared__ float4 sW[8 * 256];
  __shared__ float sP[8];
  int tid = threadIdx.x;
  const float4* W4 = (const float4*)Wr;
  for (int i = tid; i < 2048; i += 256) sW[i] = W4[i];
  if (tid < 8) sP[tid] = 0.f;
  __syncthreads();

  int lane = tid & 63, wid = tid >> 6;
  int t = blockIdx.x * 4 + wid;
  float acc[8] = {0.f, 0.f, 0.f, 0.f, 0.f, 0.f, 0.f, 0.f};
  const float4* x4 = (const float4*)(x + (size_t)t * DMODEL);
#pragma unroll
  for (int it = 0; it < 4; ++it) {
    float4 xv = x4[it * 64 + lane];
#pragma unroll
    for (int e = 0; e < 8; ++e) {
      float4 wv = sW[e * 256 + it * 64 + lane];
      acc[e] += xv.x * wv.x + xv.y * wv.y + xv.z * wv.z + xv.w * wv.w;
    }
  }
#pragma unroll
  for (int e = 0; e < 8; ++e)
    for (int off = 32; off; off >>= 1) acc[e] += __shfl_xor(acc[e], off);

  float mx = acc[0];
#pragma unroll
  for (int e = 1; e < 8; ++e) mx = fmaxf(mx, acc[e]);
  float ex[8], s = 0.f;
#pragma unroll
  for (int e = 0; e < 8; ++e) { ex[e] = expf(acc[e] - mx); s += ex[e]; }
  float inv = 1.f / s;
  int e0 = 0;
#pragma unroll
  for (int e = 1; e < 8; ++e) if (acc[e] > acc[e0]) e0 = e;
  int e1 = (e0 == 0) ? 1 : 0;
#pragma unroll
  for (int e = 0; e < 8; ++e) if (e != e0 && acc[e] > acc[e1]) e1 = e;

  if (lane == 0) {
#pragma unroll
    for (int e = 0; e < 8; ++e) atomicAdd(&sP[e], ex[e] * inv);
    atomicAdd(&cnt1[e0], 1);
    int s0 = atomicAdd(&cursor[e0], 1);
    perm[e0 * 4096 + s0] = t; pw[e0 * 4096 + s0] = ex[e0] * inv;
    int s1 = atomicAdd(&cursor[e1], 1);
    perm[e1 * 4096 + s1] = t; pw[e1 * 4096 + s1] = ex[e1] * inv;
  }
  __syncthreads();
  if (tid < 8) atomicAdd(&psum[tid], sP[tid]);
}

// ---------------- finalize: padded bases + aux loss ----------------
__global__ void finalize_kernel(const int* __restrict__ cursor,
                                const int* __restrict__ cnt1,
                                const float* __restrict__ psum,
                                int* __restrict__ base, float* __restrict__ aux_out) {
  if (threadIdx.x == 0) {
    int b = 0;
    for (int e = 0; e < 8; ++e) { base[e] = b; b += ((cursor[e] + 127) >> 7) << 7; }
    base[8] = b;  // shared expert rows start here (128-aligned)
    float aux = 0.f;
    for (int e = 0; e < 8; ++e)
      aux += ((float)cnt1[e] * (1.f / T_TOK)) * (psum[e] * (1.f / T_TOK));
    aux_out[0] = 0.01f * 8.f * aux;
  }
}

// ---------------- fused up+gate GEMM (bf16, global_load_lds, frag-major LDS) ----
__global__ __launch_bounds__(256, 2) void gemm_upgate(
    const short* __restrict__ xb,
    const short* __restrict__ wu, const short* __restrict__ wg,
    const int* __restrict__ cursor, const int* __restrict__ base,
    const int* __restrict__ perm, unsigned short* __restrict__ hbuf) {
  int e = blockIdx.z, mt = blockIdx.y, nt = blockIdx.x;
  int cnt = (e < 8) ? cursor[e] : 4096;
  if (mt * 128 >= cnt) return;
  int hb = base[e];
  const short* wuE = wu + (size_t)e * 2097152;
  const short* wgE = wg + (size_t)e * 2097152;

  __shared__ short As[8192];   // 16 groups x 64 lanes x 8 bf16 (frag-major)
  __shared__ short Bs1[8192];
  __shared__ short Bs3[8192];

  int tid = threadIdx.x;
  int lane = tid & 63, wid = tid >> 6;
  int fr = lane & 15, ko8 = (lane >> 4) * 8;
  int wr = wid >> 1, wc = wid & 1;

  size_t aOff[4];
#pragma unroll
  for (int s = 0; s < 4; ++s) {
    int g = s * 4 + wid;
    int slot = mt * 128 + (g >> 1) * 16 + fr;
    int tok = (e == 8) ? slot : ((slot < cnt) ? perm[e * 4096 + slot] : 0);
    aOff[s] = (size_t)tok * DMODEL + (g & 1) * 32 + ko8;
  }

  f32x4 acc1[4][4] = {}; f32x4 acc3[4][4] = {};

  for (int k0 = 0; k0 < DMODEL; k0 += 64) {
    int kb = k0 >> 5;
#pragma unroll
    for (int s = 0; s < 4; ++s) {
      int g = s * 4 + wid;
      gload16(xb + aOff[s] + k0, &As[g * 512 + lane * 8]);
      size_t cb = (((size_t)(nt * 8 + (g >> 1)) * 32 + kb + (g & 1)) * 64 + lane) * 8;
      gload16(wuE + cb, &Bs1[g * 512 + lane * 8]);
      gload16(wgE + cb, &Bs3[g * 512 + lane * 8]);
    }
    __syncthreads();
#pragma unroll
    for (int ksub = 0; ksub < 2; ++ksub) {
      bf16x8 af[4], b1f[4], b3f[4];
#pragma unroll
      for (int m = 0; m < 4; ++m)
        af[m] = *(const bf16x8*)&As[((wr * 4 + m) * 2 + ksub) * 512 + lane * 8];
#pragma unroll
      for (int n = 0; n < 4; ++n) {
        b1f[n] = *(const bf16x8*)&Bs1[((wc * 4 + n) * 2 + ksub) * 512 + lane * 8];
        b3f[n] = *(const bf16x8*)&Bs3[((wc * 4 + n) * 2 + ksub) * 512 + lane * 8];
      }
#pragma unroll
      for (int m = 0; m < 4; ++m)
#pragma unroll
        for (int n = 0; n < 4; ++n) {
          acc1[m][n] = __builtin_amdgcn_mfma_f32_16x16x32_bf16(af[m], b1f[n], acc1[m][n], 0, 0, 0);
          acc3[m][n] = __builtin_amdgcn_mfma_f32_16x16x32_bf16(af[m], b3f[n], acc3[m][n], 0, 0, 0);
        }
    }
    __syncthreads();
  }

  int q = lane >> 4;
#pragma unroll
  for (int m = 0; m < 4; ++m) {
#pragma unroll
    for (int n = 0; n < 4; ++n) {
      int col = nt * 128 + wc * 64 + n * 16 + fr;
      f32x4 u = acc1[m][n], g = acc3[m][n];
#pragma unroll
      for (int j = 0; j < 4; ++j) {
        int sl = mt * 128 + wr * 64 + m * 16 + q * 4 + j;
        float hv = (sl < cnt) ? gelu_erf(u[j]) * g[j] : 0.f;
        hbuf[(size_t)(hb + sl) * HDIM + col] = f2bf(hv);
      }
    }
  }
}

// ---------------- down GEMM + weighted scatter ----------------
__global__ __launch_bounds__(256, 2) void gemm_down(
    const unsigned short* __restrict__ hbuf,
    const short* __restrict__ wd,
    const int* __restrict__ cursor, const int* __restrict__ base,
    const int* __restrict__ perm, const float* __restrict__ pw,
    float* __restrict__ out) {
  int e = blockIdx.z, mt = blockIdx.y, nt = blockIdx.x;
  int cnt = (e < 8) ? cursor[e] : 4096;
  if (mt * 128 >= cnt) return;
  int hb = base[e];
  const short* wdE = wd + (size_t)e * 2097152;

  __shared__ short As[8192];
  __shared__ short Bs[8192];

  int tid = threadIdx.x;
  int lane = tid & 63, wid = tid >> 6;
  int fr = lane & 15, ko8 = (lane >> 4) * 8;
  int wr = wid >> 1, wc = wid & 1;

  size_t aOff[4];
#pragma unroll
  for (int s = 0; s < 4; ++s) {
    int g = s * 4 + wid;
    size_t row = (size_t)hb + mt * 128 + (g >> 1) * 16 + fr;
    aOff[s] = row * HDIM + (g & 1) * 32 + ko8;
  }

  f32x4 acc[4][4] = {};

  for (int k0 = 0; k0 < HDIM; k0 += 64) {
    int kb = k0 >> 5;
#pragma unroll
    for (int s = 0; s < 4; ++s) {
      int g = s * 4 + wid;
      gload16(hbuf + aOff[s] + k0, &As[g * 512 + lane * 8]);
      size_t cb = (((size_t)(nt * 8 + (g >> 1)) * 64 + kb + (g & 1)) * 64 + lane) * 8;
      gload16(wdE + cb, &Bs[g * 512 + lane * 8]);
    }
    __syncthreads();
#pragma unroll
    for (int ksub = 0; ksub < 2; ++ksub) {
      bf16x8 af[4], bf[4];
#pragma unroll
      for (int m = 0; m < 4; ++m)
        af[m] = *(const bf16x8*)&As[((wr * 4 + m) * 2 + ksub) * 512 + lane * 8];
#pragma unroll
      for (int n = 0; n < 4; ++n)
        bf[n] = *(const bf16x8*)&Bs[((wc * 4 + n) * 2 + ksub) * 512 + lane * 8];
#pragma unroll
      for (int m = 0; m < 4; ++m)
#pragma unroll
        for (int n = 0; n < 4; ++n)
          acc[m][n] = __builtin_amdgcn_mfma_f32_16x16x32_bf16(af[m], bf[n], acc[m][n], 0, 0, 0);
    }
    __syncthreads();
  }

  int q = lane >> 4;
#pragma unroll
  for (int m = 0; m < 4; ++m) {
#pragma unroll
    for (int n = 0; n < 4; ++n) {
      int col = nt * 128 + wc * 64 + n * 16 + fr;
      f32x4 a = acc[m][n];
#pragma unroll
      for (int j = 0; j < 4; ++j) {
        int sl = mt * 128 + wr * 64 + m * 16 + q * 4 + j;
        if (sl < cnt) {
          int tok; float p;
          if (e == 8) { tok = sl; p = 1.f; }
          else { tok = perm[e * 4096 + sl]; p = pw[e * 4096 + sl]; }
          atomicAdd(&out[(size_t)tok * DMODEL + col], p * a[j]);
        }
      }
    }
  }
}

extern "C" void kernel_launch(void* const* d_in, const int* in_sizes, int n_in,
                              void* d_out, int out_size, void* d_ws, size_t ws_size,
                              hipStream_t stream) {
  const float* x   = (const float*)d_in[0];
  const float* Wr  = (const float*)d_in[1];
  const float* w1  = (const float*)d_in[2];
  const float* w2  = (const float*)d_in[3];
  const float* w3  = (const float*)d_in[4];
  const float* w1s = (const float*)d_in[5];
  const float* w2s = (const float*)d_in[6];
  const float* w3s = (const float*)d_in[7];
  float* out = (float*)d_out;

  char* ws = (char*)d_ws;
  const size_t HBUF_OFF = 0;                       // 16384*2048 bf16 = 67108864 B
  const size_t XB_OFF   = 67108864;                // 4096*1024 bf16 = 8388608 B
  const size_t WU_OFF   = XB_OFF + 8388608;        // 9*2M bf16 = 37748736 B
  const size_t WG_OFF   = WU_OFF + 37748736;
  const size_t WD_OFF   = WG_OFF + 37748736;
  const size_t PERM_OFF = WD_OFF + 37748736;       // 8*4096 int
  const size_t PW_OFF   = PERM_OFF + 131072;
  const size_t CTRL_OFF = PW_OFF + 131072;

  unsigned short* hbuf = (unsigned short*)(ws + HBUF_OFF);
  short* xb = (short*)(ws + XB_OFF);
  short* wu = (short*)(ws + WU_OFF);
  short* wg = (short*)(ws + WG_OFF);
  short* wd = (short*)(ws + WD_OFF);
  int*   perm   = (int*)(ws + PERM_OFF);
  float* pw     = (float*)(ws + PW_OFF);
  int*   cursor = (int*)(ws + CTRL_OFF);
  int*   cnt1   = (int*)(ws + CTRL_OFF + 64);
  float* psum   = (float*)(ws + CTRL_OFF + 128);
  int*   base   = (int*)(ws + CTRL_OFF + 192);

  hipMemsetAsync(d_out, 0, (size_t)out_size * sizeof(float), stream);
  hipMemsetAsync(ws + CTRL_OFF, 0, 256, stream);

  convert_x<<<2048, 256, 0, stream>>>(x, xb);
  convert_w13<<<9216, 256, 0, stream>>>(w1, w3, w1s, w3s, wu, wg);
  convert_w2<<<9216, 256, 0, stream>>>(w2, w2s, wd);
  router_kernel<<<1024, 256, 0, stream>>>(x, Wr, cursor, cnt1, psum, perm, pw);
  finalize_kernel<<<1, 64, 0, stream>>>(cursor, cnt1, psum, base,
                                        out + (size_t)T_TOK * DMODEL);
  gemm_upgate<<<dim3(16, 32, 9), 256, 0, stream>>>(xb, wu, wg, cursor, base, perm, hbuf);
  gemm_down<<<dim3(8, 32, 9), 256, 0, stream>>>(hbuf, wd, cursor, base, perm, pw, out);
}

// Round 3
// 459.194 us; speedup vs baseline: 1.4506x; 1.0642x over previous
//
#include <hip/hip_runtime.h>
#include <hip/hip_bf16.h>
#include <cstdint>

#define T_TOK 4096
#define DMODEL 1024
#define HDIM 2048

typedef short bf16x8 __attribute__((ext_vector_type(8)));
typedef float f32x4 __attribute__((ext_vector_type(4)));
typedef uint32_t u32x4 __attribute__((ext_vector_type(4)));

__device__ __forceinline__ uint32_t cvt_pk_bf16(float lo, float hi) {
  uint32_t d;
  asm("v_cvt_pk_bf16_f32 %0, %1, %2" : "=v"(d) : "v"(lo), "v"(hi));
  return d;
}
__device__ __forceinline__ unsigned short f2bf(float f) {
  uint32_t d;
  asm("v_cvt_pk_bf16_f32 %0, %1, %1" : "=v"(d) : "v"(f));
  return (unsigned short)d;
}
__device__ __forceinline__ float gelu_erf(float v) {
  return 0.5f * v * (1.0f + erff(v * 0.70710678118654752f));
}
__device__ __forceinline__ void gload16(const void* g, void* lds) {
  __builtin_amdgcn_global_load_lds((const __attribute__((address_space(1))) void*)g,
                                   (__attribute__((address_space(3))) void*)lds, 16, 0, 0);
}
__device__ __forceinline__ u32x4 pk8(const float* s) {
  float4 v0 = ((const float4*)s)[0], v1 = ((const float4*)s)[1];
  u32x4 p = {cvt_pk_bf16(v0.x, v0.y), cvt_pk_bf16(v0.z, v0.w),
             cvt_pk_bf16(v1.x, v1.y), cvt_pk_bf16(v1.z, v1.w)};
  return p;
}

// ---------------- merged weight conversion (fragment-major bf16) ----------------
// wu/wg per expert: [h16:128][d32:32][lane:64][8]   wd per expert: [d16:64][h32:64][lane:64][8]
__global__ __launch_bounds__(256) void convert_w(
    const float* __restrict__ w1, const float* __restrict__ w3,
    const float* __restrict__ w1s, const float* __restrict__ w3s,
    const float* __restrict__ w2, const float* __restrict__ w2s,
    short* __restrict__ wu, short* __restrict__ wg, short* __restrict__ wd) {
  int bid = blockIdx.x;
  if (bid < 9216) {
    int id = bid * 256 + threadIdx.x;
    int e = id >> 18, rem = id & 262143;
    int h16 = rem >> 11, d32 = (rem >> 6) & 31, ln = rem & 63;
    size_t so = (size_t)(h16 * 16 + (ln & 15)) * DMODEL + d32 * 32 + (ln >> 4) * 8;
    const float* s1 = (e < 8) ? w1 + (size_t)e * 2097152 + so : w1s + so;
    const float* s3 = (e < 8) ? w3 + (size_t)e * 2097152 + so : w3s + so;
    *(u32x4*)(wu + (size_t)id * 8) = pk8(s1);
    *(u32x4*)(wg + (size_t)id * 8) = pk8(s3);
  } else {
    int id = (bid - 9216) * 256 + threadIdx.x;
    int e = id >> 18, rem = id & 262143;
    int d16 = rem >> 12, h32 = (rem >> 6) & 63, ln = rem & 63;
    size_t so = (size_t)(d16 * 16 + (ln & 15)) * HDIM + h32 * 32 + (ln >> 4) * 8;
    const float* s2 = (e < 8) ? w2 + (size_t)e * 2097152 + so : w2s + so;
    *(u32x4*)(wd + (size_t)id * 8) = pk8(s2);
  }
}

// ---------------- router: one wave per token; also emits xb (bf16 x) ----------------
__global__ __launch_bounds__(256) void router_kernel(
    const float* __restrict__ x, const float* __restrict__ Wr,
    int* __restrict__ cursor, int* __restrict__ cnt1,
    float* __restrict__ psum, int* __restrict__ perm, float* __restrict__ pw,
    short* __restrict__ xb) {
  __shared__ float4 sW[8 * 256];
  __shared__ float sP[8];
  int tid = threadIdx.x;
  const float4* W4 = (const float4*)Wr;
  for (int i = tid; i < 2048; i += 256) sW[i] = W4[i];
  if (tid < 8) sP[tid] = 0.f;
  __syncthreads();

  int lane = tid & 63, wid = tid >> 6;
  int t = blockIdx.x * 4 + wid;
  float acc[8] = {0.f, 0.f, 0.f, 0.f, 0.f, 0.f, 0.f, 0.f};
  const float4* x4 = (const float4*)(x + (size_t)t * DMODEL);
#pragma unroll
  for (int it = 0; it < 4; ++it) {
    float4 xv = x4[it * 64 + lane];
    uint2 pk = {cvt_pk_bf16(xv.x, xv.y), cvt_pk_bf16(xv.z, xv.w)};
    *(uint2*)(xb + (size_t)t * DMODEL + it * 256 + lane * 4) = pk;
#pragma unroll
    for (int e = 0; e < 8; ++e) {
      float4 wv = sW[e * 256 + it * 64 + lane];
      acc[e] += xv.x * wv.x + xv.y * wv.y + xv.z * wv.z + xv.w * wv.w;
    }
  }
#pragma unroll
  for (int e = 0; e < 8; ++e)
    for (int off = 32; off; off >>= 1) acc[e] += __shfl_xor(acc[e], off);

  float mx = acc[0];
#pragma unroll
  for (int e = 1; e < 8; ++e) mx = fmaxf(mx, acc[e]);
  float ex[8], s = 0.f;
#pragma unroll
  for (int e = 0; e < 8; ++e) { ex[e] = expf(acc[e] - mx); s += ex[e]; }
  float inv = 1.f / s;
  int e0 = 0;
#pragma unroll
  for (int e = 1; e < 8; ++e) if (acc[e] > acc[e0]) e0 = e;
  int e1 = (e0 == 0) ? 1 : 0;
#pragma unroll
  for (int e = 0; e < 8; ++e) if (e != e0 && acc[e] > acc[e1]) e1 = e;

  if (lane == 0) {
#pragma unroll
    for (int e = 0; e < 8; ++e) atomicAdd(&sP[e], ex[e] * inv);
    atomicAdd(&cnt1[e0], 1);
    int s0 = atomicAdd(&cursor[e0], 1);
    perm[e0 * 4096 + s0] = t; pw[e0 * 4096 + s0] = ex[e0] * inv;
    int s1 = atomicAdd(&cursor[e1], 1);
    perm[e1 * 4096 + s1] = t; pw[e1 * 4096 + s1] = ex[e1] * inv;
  }
  __syncthreads();
  if (tid < 8) atomicAdd(&psum[tid], sP[tid]);
}

// ---------------- finalize: padded bases + aux loss ----------------
__global__ void finalize_kernel(const int* __restrict__ cursor,
                                const int* __restrict__ cnt1,
                                const float* __restrict__ psum,
                                int* __restrict__ base, float* __restrict__ aux_out) {
  if (threadIdx.x == 0) {
    int b = 0;
    for (int e = 0; e < 8; ++e) { base[e] = b; b += ((cursor[e] + 127) >> 7) << 7; }
    base[8] = b;
    float aux = 0.f;
    for (int e = 0; e < 8; ++e)
      aux += ((float)cnt1[e] * (1.f / T_TOK)) * (psum[e] * (1.f / T_TOK));
    aux_out[0] = 0.01f * 8.f * aux;
  }
}

// ---------------- fused up+gate GEMM: 2-phase double-buffered, BK=32 ----------------
__global__ __launch_bounds__(256, 2) void gemm_upgate(
    const short* __restrict__ xb,
    const short* __restrict__ wu, const short* __restrict__ wg,
    const int* __restrict__ cursor, const int* __restrict__ base,
    const int* __restrict__ perm, unsigned short* __restrict__ hbuf) {
  int e = blockIdx.z, mt = blockIdx.y, nt = blockIdx.x;
  int cnt = (e < 8) ? cursor[e] : 4096;
  if (mt * 128 >= cnt) return;
  int hb = base[e];
  const short* wuE = wu + (size_t)e * 2097152;
  const short* wgE = wg + (size_t)e * 2097152;

  __shared__ short As[2][4096], Bs1[2][4096], Bs3[2][4096];

  int tid = threadIdx.x, lane = tid & 63, wid = tid >> 6;
  int fr = lane & 15, ko8 = (lane >> 4) * 8;
  int wr = wid >> 1, wc = wid & 1;

  size_t aOff[2], bOff[2];
#pragma unroll
  for (int s = 0; s < 2; ++s) {
    int g = s * 4 + wid;
    int slot = mt * 128 + g * 16 + fr;
    int tok = (e == 8) ? slot : ((slot < cnt) ? perm[e * 4096 + slot] : 0);
    aOff[s] = (size_t)tok * DMODEL + ko8;
    bOff[s] = ((size_t)(nt * 8 + g) * 32 * 64 + lane) * 8;
  }

  f32x4 acc1[4][4] = {}, acc3[4][4] = {};

  auto stage = [&](int buf, int it) {
#pragma unroll
    for (int s = 0; s < 2; ++s) {
      int g = s * 4 + wid;
      gload16(xb + aOff[s] + it * 32, &As[buf][g * 512 + lane * 8]);
      size_t cb = bOff[s] + (size_t)it * 512;
      gload16(wuE + cb, &Bs1[buf][g * 512 + lane * 8]);
      gload16(wgE + cb, &Bs3[buf][g * 512 + lane * 8]);
    }
  };
  auto compute = [&](int buf) {
    bf16x8 af[4], b1f[4], b3f[4];
#pragma unroll
    for (int m = 0; m < 4; ++m)
      af[m] = *(const bf16x8*)&As[buf][(wr * 4 + m) * 512 + lane * 8];
#pragma unroll
    for (int n = 0; n < 4; ++n) {
      b1f[n] = *(const bf16x8*)&Bs1[buf][(wc * 4 + n) * 512 + lane * 8];
      b3f[n] = *(const bf16x8*)&Bs3[buf][(wc * 4 + n) * 512 + lane * 8];
    }
    __builtin_amdgcn_s_setprio(1);
#pragma unroll
    for (int m = 0; m < 4; ++m)
#pragma unroll
      for (int n = 0; n < 4; ++n) {
        acc1[m][n] = __builtin_amdgcn_mfma_f32_16x16x32_bf16(af[m], b1f[n], acc1[m][n], 0, 0, 0);
        acc3[m][n] = __builtin_amdgcn_mfma_f32_16x16x32_bf16(af[m], b3f[n], acc3[m][n], 0, 0, 0);
      }
    __builtin_amdgcn_s_setprio(0);
  };

  stage(0, 0);
  __syncthreads();
  int cur = 0;
  for (int it = 1; it < 32; ++it) {
    stage(cur ^ 1, it);
    compute(cur);
    __syncthreads();
    cur ^= 1;
  }
  compute(cur);

  int q = lane >> 4;
#pragma unroll
  for (int m = 0; m < 4; ++m) {
#pragma unroll
    for (int n = 0; n < 4; ++n) {
      int col = nt * 128 + wc * 64 + n * 16 + fr;
      f32x4 u = acc1[m][n], g = acc3[m][n];
#pragma unroll
      for (int j = 0; j < 4; ++j) {
        int sl = mt * 128 + wr * 64 + m * 16 + q * 4 + j;
        float hv = (sl < cnt) ? gelu_erf(u[j]) * g[j] : 0.f;
        hbuf[(size_t)(hb + sl) * HDIM + col] = f2bf(hv);
      }
    }
  }
}

// ---------------- down GEMM: 2-phase double-buffered, BK=32, weighted scatter ----
__global__ __launch_bounds__(256, 2) void gemm_down(
    const unsigned short* __restrict__ hbuf,
    const short* __restrict__ wd,
    const int* __restrict__ cursor, const int* __restrict__ base,
    const int* __restrict__ perm, const float* __restrict__ pw,
    float* __restrict__ out) {
  int e = blockIdx.z, mt = blockIdx.y, nt = blockIdx.x;
  int cnt = (e < 8) ? cursor[e] : 4096;
  if (mt * 128 >= cnt) return;
  int hb = base[e];
  const short* wdE = wd + (size_t)e * 2097152;

  __shared__ short As[2][4096], Bs[2][4096];

  int tid = threadIdx.x, lane = tid & 63, wid = tid >> 6;
  int fr = lane & 15, ko8 = (lane >> 4) * 8;
  int wr = wid >> 1, wc = wid & 1;

  size_t aOff[2], bOff[2];
#pragma unroll
  for (int s = 0; s < 2; ++s) {
    int g = s * 4 + wid;
    aOff[s] = (size_t)(hb + mt * 128 + g * 16 + fr) * HDIM + ko8;
    bOff[s] = ((size_t)(nt * 8 + g) * 64 * 64 + lane) * 8;
  }

  f32x4 acc[4][4] = {};

  auto stage = [&](int buf, int it) {
#pragma unroll
    for (int s = 0; s < 2; ++s) {
      int g = s * 4 + wid;
      gload16(hbuf + aOff[s] + it * 32, &As[buf][g * 512 + lane * 8]);
      gload16(wdE + bOff[s] + (size_t)it * 512, &Bs[buf][g * 512 + lane * 8]);
    }
  };
  auto compute = [&](int buf) {
    bf16x8 af[4], bf[4];
#pragma unroll
    for (int m = 0; m < 4; ++m)
      af[m] = *(const bf16x8*)&As[buf][(wr * 4 + m) * 512 + lane * 8];
#pragma unroll
    for (int n = 0; n < 4; ++n)
      bf[n] = *(const bf16x8*)&Bs[buf][(wc * 4 + n) * 512 + lane * 8];
    __builtin_amdgcn_s_setprio(1);
#pragma unroll
    for (int m = 0; m < 4; ++m)
#pragma unroll
      for (int n = 0; n < 4; ++n)
        acc[m][n] = __builtin_amdgcn_mfma_f32_16x16x32_bf16(af[m], bf[n], acc[m][n], 0, 0, 0);
    __builtin_amdgcn_s_setprio(0);
  };

  stage(0, 0);
  __syncthreads();
  int cur = 0;
  for (int it = 1; it < 64; ++it) {
    stage(cur ^ 1, it);
    compute(cur);
    __syncthreads();
    cur ^= 1;
  }
  compute(cur);

  int q = lane >> 4;
#pragma unroll
  for (int m = 0; m < 4; ++m) {
#pragma unroll
    for (int n = 0; n < 4; ++n) {
      int col = nt * 128 + wc * 64 + n * 16 + fr;
      f32x4 a = acc[m][n];
#pragma unroll
      for (int j = 0; j < 4; ++j) {
        int sl = mt * 128 + wr * 64 + m * 16 + q * 4 + j;
        if (sl < cnt) {
          int tok; float p;
          if (e == 8) { tok = sl; p = 1.f; }
          else { tok = perm[e * 4096 + sl]; p = pw[e * 4096 + sl]; }
          atomicAdd(&out[(size_t)tok * DMODEL + col], p * a[j]);
        }
      }
    }
  }
}

extern "C" void kernel_launch(void* const* d_in, const int* in_sizes, int n_in,
                              void* d_out, int out_size, void* d_ws, size_t ws_size,
                              hipStream_t stream) {
  const float* x   = (const float*)d_in[0];
  const float* Wr  = (const float*)d_in[1];
  const float* w1  = (const float*)d_in[2];
  const float* w2  = (const float*)d_in[3];
  const float* w3  = (const float*)d_in[4];
  const float* w1s = (const float*)d_in[5];
  const float* w2s = (const float*)d_in[6];
  const float* w3s = (const float*)d_in[7];
  float* out = (float*)d_out;

  char* ws = (char*)d_ws;
  const size_t HBUF_OFF = 0;                       // 16384*2048 bf16
  const size_t XB_OFF   = 67108864;                // 4096*1024 bf16
  const size_t WU_OFF   = XB_OFF + 8388608;        // 9*2M bf16
  const size_t WG_OFF   = WU_OFF + 37748736;
  const size_t WD_OFF   = WG_OFF + 37748736;
  const size_t PERM_OFF = WD_OFF + 37748736;
  const size_t PW_OFF   = PERM_OFF + 131072;
  const size_t CTRL_OFF = PW_OFF + 131072;

  unsigned short* hbuf = (unsigned short*)(ws + HBUF_OFF);
  short* xb = (short*)(ws + XB_OFF);
  short* wu = (short*)(ws + WU_OFF);
  short* wg = (short*)(ws + WG_OFF);
  short* wd = (short*)(ws + WD_OFF);
  int*   perm   = (int*)(ws + PERM_OFF);
  float* pw     = (float*)(ws + PW_OFF);
  int*   cursor = (int*)(ws + CTRL_OFF);
  int*   cnt1   = (int*)(ws + CTRL_OFF + 64);
  float* psum   = (float*)(ws + CTRL_OFF + 128);
  int*   base   = (int*)(ws + CTRL_OFF + 192);

  hipMemsetAsync(d_out, 0, (size_t)out_size * sizeof(float), stream);
  hipMemsetAsync(ws + CTRL_OFF, 0, 256, stream);

  router_kernel<<<1024, 256, 0, stream>>>(x, Wr, cursor, cnt1, psum, perm, pw, xb);
  finalize_kernel<<<1, 64, 0, stream>>>(cursor, cnt1, psum, base,
                                        out + (size_t)T_TOK * DMODEL);
  convert_w<<<18432, 256, 0, stream>>>(w1, w3, w1s, w3s, w2, w2s, wu, wg, wd);
  gemm_upgate<<<dim3(16, 32, 9), 256, 0, stream>>>(xb, wu, wg, cursor, base, perm, hbuf);
  gemm_down<<<dim3(8, 32, 9), 256, 0, stream>>>(hbuf, wd, cursor, base, perm, pw, out);
}